// Round 1
// baseline (1170.689 us; speedup 1.0000x reference)
//
#include <hip/hip_runtime.h>

#define Hdim 128
#define Tlen 512
#define BT 8      // batch rows per block
#define STR 136   // padded LDS row stride in bf16 elems (16B-aligned, odd 16B-units)

typedef __attribute__((ext_vector_type(8))) short s16x8;
typedef __attribute__((ext_vector_type(8))) __bf16 bf16x8;
typedef __attribute__((ext_vector_type(4))) float f32x4;

__device__ __forceinline__ f32x4 mfma_bf16(s16x8 a, s16x8 b, f32x4 c) {
  return __builtin_amdgcn_mfma_f32_16x16x32_bf16(
      __builtin_bit_cast(bf16x8, a), __builtin_bit_cast(bf16x8, b), c, 0, 0, 0);
}

__device__ __forceinline__ unsigned short f2bf(float f) {
  unsigned u = __builtin_bit_cast(unsigned, f);
  return (unsigned short)((u + 0x7FFFu + ((u >> 16) & 1u)) >> 16);
}
__device__ __forceinline__ float bf2f(unsigned short s) {
  return __builtin_bit_cast(float, ((unsigned)s) << 16);
}
__device__ __forceinline__ float sigm(float x) { return 1.0f / (1.0f + __expf(-x)); }
__device__ __forceinline__ float tanhx(float x) {
  float e = __expf(2.0f * x);          // x>>0: e=inf -> 1; x<<0: e->0 -> -1
  return 1.0f - 2.0f / (e + 1.0f);
}

// Each block: 8 batch rows, all 512 timesteps.
// gates-major MFMA 16x16x32: A = W_hh chunk (M=gate rows, register-stationary,
// split hi/lo bf16), B = h^T (cols 0-7 = h_hi rows, cols 8-15 = h_lo rows),
// two A-passes (hi, lo) into one accumulator -> all 4 split products.
// gate = D[m][b] + D[m][b+8] via shfl_xor(8).
// Wave w owns M-tiles {w+4s}: all 4 gate types of units k in
// [16w,16w+16) u [16w+64,16w+80) live in-lane -> c,h update in registers.
__global__ __launch_bounds__(256, 1)
void lstm_disc_kernel(const float* __restrict__ x, const float* __restrict__ hx0,
                      const float* __restrict__ cx0, const float* __restrict__ W_ih,
                      const float* __restrict__ W_hh, const float* __restrict__ b_ih,
                      const float* __restrict__ b_hh, const float* __restrict__ W_mlp,
                      const float* __restrict__ b_mlp, float* __restrict__ out) {
  __shared__ unsigned short hbuf[2][16 * STR];

  const int tid  = threadIdx.x;
  const int w    = tid >> 6;         // wave 0..3
  const int lane = tid & 63;
  const int l16  = lane & 15;        // B col n / A row m
  const int quad = lane >> 4;        // 0..3
  const int b0   = blockIdx.x * BT;
  const int bb   = l16 & 7;          // batch row within block
  const bool real = (l16 < 8);
  const int rbase = real ? 0 : 2;    // which C-regs this lane owns for update

  // ---- W_hh fragments (A layout: A[m=l16][k=quad*8+e]), hi/lo split ----
  s16x8 whi[8][4], wlo[8][4];
#pragma unroll
  for (int s = 0; s < 8; s++) {
    const int t = w + 4 * s;               // M-tile 0..31
    const int j = t * 16 + l16;            // gate row 0..511
#pragma unroll
    for (int q = 0; q < 4; q++) {
      const float* p = W_hh + j * Hdim + q * 32 + quad * 8;
      s16x8 hi8, lo8;
#pragma unroll
      for (int e = 0; e < 8; e++) {
        float v = p[e];
        unsigned short h = f2bf(v);
        unsigned short l = f2bf(v - bf2f(h));
        ((short*)&hi8)[e] = (short)h;
        ((short*)&lo8)[e] = (short)l;
      }
      whi[s][q] = hi8;
      wlo[s][q] = lo8;
    }
  }

  // ---- per-lane W_ih & bias in C/D layout (row m = quad*4+r) ----
  float wih_r[8][4], bias_r[8][4];
#pragma unroll
  for (int s = 0; s < 8; s++) {
    const int t = w + 4 * s;
#pragma unroll
    for (int r = 0; r < 4; r++) {
      const int j = t * 16 + quad * 4 + r;
      wih_r[s][r]  = W_ih[j];
      bias_r[s][r] = b_ih[j] + b_hh[j];
    }
  }

  // ---- h0 -> LDS (hi rows 0-7, lo rows 8-15) ----
  for (int i = tid; i < BT * Hdim; i += 256) {
    const int b = i >> 7, k = i & 127;
    float v = hx0[(b0 + b) * Hdim + k];
    unsigned short h = f2bf(v);
    hbuf[0][b * STR + k]       = h;
    hbuf[0][(b + 8) * STR + k] = f2bf(v - bf2f(h));
  }

  // ---- c0 -> registers (each lane owns 4 (b,k) cells, disjoint cover) ----
  float c[2][2];
#pragma unroll
  for (int u = 0; u < 2; u++)
#pragma unroll
    for (int r2 = 0; r2 < 2; r2++) {
      const int k = 16 * w + 64 * u + quad * 4 + rbase + r2;
      c[u][r2] = cx0[(b0 + bb) * Hdim + k];
    }

  float xv = x[(b0 + bb) * Tlen + 0];

  __syncthreads();

  for (int t = 0; t < Tlen; t++) {
    const int cur = t & 1, nxt = cur ^ 1;

    // B fragments: B[k=quad*8+e][n=l16]; rows 0-7 hi, 8-15 lo
    s16x8 bfrag[4];
#pragma unroll
    for (int q = 0; q < 4; q++)
      bfrag[q] = *(const s16x8*)&hbuf[cur][l16 * STR + q * 32 + quad * 8];

    // acc init with gates_x (fp32-exact); lo-columns start at 0
    f32x4 acc[8];
#pragma unroll
    for (int s = 0; s < 8; s++) {
      f32x4 a;
#pragma unroll
      for (int r = 0; r < 4; r++)
        a[r] = real ? (xv * wih_r[s][r] + bias_r[s][r]) : 0.0f;
      acc[s] = a;
    }

    // MFMA: two A-passes (hi, lo) x 4 K-tiles, same accumulator
#pragma unroll
    for (int s = 0; s < 8; s++) {
      f32x4 a = acc[s];
#pragma unroll
      for (int q = 0; q < 4; q++) a = mfma_bf16(whi[s][q], bfrag[q], a);
#pragma unroll
      for (int q = 0; q < 4; q++) a = mfma_bf16(wlo[s][q], bfrag[q], a);
      acc[s] = a;
    }

    if (t + 1 < Tlen) xv = x[(b0 + bb) * Tlen + (t + 1)];

    // cross-add hi/lo column halves; each lane keeps only its 2 owned regs
    float G[8][2];
#pragma unroll
    for (int s = 0; s < 8; s++) {
#pragma unroll
      for (int r2 = 0; r2 < 2; r2++) {
        float mine = real ? acc[s][r2] : acc[s][2 + r2];
        float send = real ? acc[s][2 + r2] : acc[s][r2];
        G[s][r2] = mine + __shfl_xor(send, 8);
      }
    }

    // LSTM pointwise update, in registers; write new h (hi/lo) to LDS
#pragma unroll
    for (int u = 0; u < 2; u++) {
      unsigned hi_pack = 0, lo_pack = 0;
#pragma unroll
      for (int r2 = 0; r2 < 2; r2++) {
        float iv = sigm(G[0 + u][r2]);
        float fv = sigm(G[2 + u][r2]);
        float gv = tanhx(G[4 + u][r2]);
        float ov = sigm(G[6 + u][r2]);
        float cn = fv * c[u][r2] + iv * gv;
        c[u][r2] = cn;
        float hv = ov * tanhx(cn);
        unsigned short hh = f2bf(hv);
        unsigned short hl = f2bf(hv - bf2f(hh));
        hi_pack |= (unsigned)hh << (16 * r2);
        lo_pack |= (unsigned)hl << (16 * r2);
      }
      const int kb = 16 * w + 64 * u + quad * 4 + rbase;
      *(unsigned*)&hbuf[nxt][bb * STR + kb]       = hi_pack;
      *(unsigned*)&hbuf[nxt][(bb + 8) * STR + kb] = lo_pack;
    }

    __syncthreads();
  }

  // ---- epilogue: out[b] = sigmoid(h . W_mlp + b_mlp); final h in hbuf[0] ----
  if (tid < BT) {
    float s = 0.0f;
#pragma unroll 8
    for (int k = 0; k < Hdim; k++) {
      float hv = bf2f(hbuf[0][tid * STR + k]) + bf2f(hbuf[0][(tid + 8) * STR + k]);
      s += hv * W_mlp[k];
    }
    out[b0 + tid] = sigm(s + b_mlp[0]);
  }
}

extern "C" void kernel_launch(void* const* d_in, const int* in_sizes, int n_in,
                              void* d_out, int out_size, void* d_ws, size_t ws_size,
                              hipStream_t stream) {
  const float* x     = (const float*)d_in[0];
  const float* hx0   = (const float*)d_in[1];
  const float* cx0   = (const float*)d_in[2];
  const float* W_ih  = (const float*)d_in[3];
  const float* W_hh  = (const float*)d_in[4];
  const float* b_ih  = (const float*)d_in[5];
  const float* b_hh  = (const float*)d_in[6];
  const float* W_mlp = (const float*)d_in[7];
  const float* b_mlp = (const float*)d_in[8];
  float* out = (float*)d_out;

  const int B = in_sizes[1] / Hdim;   // hx0 is [B, H]
  dim3 grid(B / BT), block(256);
  lstm_disc_kernel<<<grid, block, 0, stream>>>(x, hx0, cx0, W_ih, W_hh, b_ih,
                                               b_hh, W_mlp, b_mlp, out);
}

// Round 2
// 564.711 us; speedup vs baseline: 2.0731x; 2.0731x over previous
//
#include <hip/hip_runtime.h>

#define Hdim 128
#define Tlen 512
#define BT 8      // batch rows per block
#define STR 136   // padded LDS row stride in fp16 elems (272B = 17x16B, 16B-aligned)

typedef __attribute__((ext_vector_type(8))) _Float16 f16x8;
typedef __attribute__((ext_vector_type(2))) _Float16 f16x2;
typedef __attribute__((ext_vector_type(4))) float f32x4;

__device__ __forceinline__ f32x4 mfma_f16(f16x8 a, f16x8 b, f32x4 c) {
  return __builtin_amdgcn_mfma_f32_16x16x32_f16(a, b, c, 0, 0, 0);
}
__device__ __forceinline__ float sigm(float x) {
  // 1/(1+2^(-x*log2e)); x->-inf: rcp(inf)=0; x->+inf: rcp(1+0)=1
  return __builtin_amdgcn_rcpf(1.0f + __builtin_amdgcn_exp2f(x * -1.44269504f));
}
__device__ __forceinline__ float tanhx(float x) {
  // 1 - 2/(2^(2x*log2e)+1); saturates correctly at +-1
  float e = __builtin_amdgcn_exp2f(x * 2.88539008f);
  return 1.0f - 2.0f * __builtin_amdgcn_rcpf(e + 1.0f);
}

// 256 blocks x 512 threads (8 waves, 2/SIMD). Block owns 8 batch rows, all T.
// MFMA 16x16x32 f16, gates-major: M=512 gate rows (32 tiles), N=16 (cols 0-7 =
// h_hi batch cols, cols 8-15 = h_lo residual cols), K=128 (+1 extra K-tile
// carrying [x,1] x [W_ih,b] so gates_x+bias ride the MFMA).
// Wave w owns tiles {w+8s}, s=0..3 = gate types i,f,g,o of units 16w..16w+15
// -> full LSTM pointwise update in registers (c fp32-resident, 2 cells/lane).
// Single-pass fp16 W (no hi/lo split): ~2.4e-4 rel W error, way under the
// 9.7e-3 threshold (round-1 hi/lo bf16 scored absmax 0.0). No spills: A-frags
// are 80 VGPRs/lane vs 256 in round 1 (whose 61.7MB WRITE_SIZE was scratch).
__global__ __launch_bounds__(512, 2)
void lstm_disc_kernel(const float* __restrict__ x, const float* __restrict__ hx0,
                      const float* __restrict__ cx0, const float* __restrict__ W_ih,
                      const float* __restrict__ W_hh, const float* __restrict__ b_ih,
                      const float* __restrict__ b_hh, const float* __restrict__ W_mlp,
                      const float* __restrict__ b_mlp, float* __restrict__ out) {
  __shared__ _Float16 hbuf[2][16 * STR];
  __shared__ float xbuf[Tlen * BT];   // [t*8+b] -> conflict-free 8-lane read

  const int tid  = threadIdx.x;
  const int w    = tid >> 6;          // wave 0..7
  const int lane = tid & 63;
  const int l16  = lane & 15;         // B col n / A row m
  const int quad = lane >> 4;         // 0..3
  const int b0   = blockIdx.x * BT;
  const int bb   = l16 & 7;           // batch row within block
  const bool hi_col = (l16 < 8);
  const int rbase = hi_col ? 0 : 2;   // C-regs this lane owns for the update

  // ---- A fragments: W_hh (fp16) + extra tile [W_ih | bias | 0...] ----
  f16x8 wh[4][4], wx[4];
#pragma unroll
  for (int s = 0; s < 4; s++) {
    const int j = 16 * w + 128 * s + l16;       // gate row, type s
#pragma unroll
    for (int q = 0; q < 4; q++) {
      const float* p = W_hh + j * Hdim + q * 32 + quad * 8;
      f16x8 f;
#pragma unroll
      for (int e = 0; e < 8; e++) f[e] = (_Float16)p[e];
      wh[s][q] = f;
    }
    f16x8 g = 0;
    if (quad == 0) {
      g[0] = (_Float16)W_ih[j];
      g[1] = (_Float16)(b_ih[j] + b_hh[j]);
    }
    wx[s] = g;
  }

  // ---- stage x for this block's batch rows into LDS ----
  for (int i = tid; i < BT * Tlen; i += 512) {
    const int t = i >> 3, b = i & 7;
    xbuf[i] = x[(b0 + b) * Tlen + t];
  }

  // ---- h0 -> LDS: rows 0-7 fp16 hi, rows 8-15 fp16 residual ----
  for (int i = tid; i < BT * Hdim; i += 512) {
    const int b = i >> 7, k = i & 127;
    float v = hx0[(b0 + b) * Hdim + k];
    _Float16 h = (_Float16)v;
    hbuf[0][b * STR + k]       = h;
    hbuf[0][(b + 8) * STR + k] = (_Float16)(v - (float)h);
  }

  // ---- c0 -> registers: lane owns units kb,kb+1 of batch bb (fp32 exact) ----
  const int kb = 16 * w + 4 * quad + rbase;     // even
  float c0v = cx0[(b0 + bb) * Hdim + kb];
  float c1v = cx0[(b0 + bb) * Hdim + kb + 1];
  float c[2] = {c0v, c1v};

  __syncthreads();

  for (int t = 0; t < Tlen; t++) {
    const int cur = t & 1, nxt = cur ^ 1;

    // B frags: B[k=quad*8+e][n=l16]
    f16x8 bfrag[4];
#pragma unroll
    for (int q = 0; q < 4; q++)
      bfrag[q] = *(const f16x8*)&hbuf[cur][l16 * STR + q * 32 + quad * 8];

    // extra K-tile B col: [x_t, 1, 0...] in hi columns only
    f16x8 bx = 0;
    if (quad == 0 && hi_col) {
      bx[0] = (_Float16)xbuf[t * 8 + l16];
      bx[1] = (_Float16)1.0f;
    }

    f32x4 acc[4];
#pragma unroll
    for (int s = 0; s < 4; s++) {
      f32x4 a = {0.0f, 0.0f, 0.0f, 0.0f};
      a = mfma_f16(wx[s], bx, a);
#pragma unroll
      for (int q = 0; q < 4; q++) a = mfma_f16(wh[s][q], bfrag[q], a);
      acc[s] = a;
    }

    // cross-add hi/lo column halves; each lane keeps its 2 owned rows
    float G[4][2];
#pragma unroll
    for (int s = 0; s < 4; s++) {
#pragma unroll
      for (int r2 = 0; r2 < 2; r2++) {
        float mine = acc[s][rbase + r2];
        float send = acc[s][(rbase ^ 2) + r2];
        G[s][r2] = mine + __shfl_xor(send, 8);
      }
    }

    // LSTM pointwise (registers); write new h (hi + residual) to LDS
    f16x2 hhp, hlp;
#pragma unroll
    for (int r2 = 0; r2 < 2; r2++) {
      float iv = sigm(G[0][r2]);
      float fv = sigm(G[1][r2]);
      float gv = tanhx(G[2][r2]);
      float ov = sigm(G[3][r2]);
      float cn = fv * c[r2] + iv * gv;
      c[r2] = cn;
      float hv = ov * tanhx(cn);
      _Float16 hh = (_Float16)hv;
      hhp[r2] = hh;
      hlp[r2] = (_Float16)(hv - (float)hh);
    }
    *(f16x2*)&hbuf[nxt][bb * STR + kb]       = hhp;
    *(f16x2*)&hbuf[nxt][(bb + 8) * STR + kb] = hlp;

    __syncthreads();
  }

  // ---- epilogue: out[b] = sigmoid(h . W_mlp + b_mlp); final h in hbuf[0] ----
  if (tid < BT) {
    float s = 0.0f;
#pragma unroll 8
    for (int k = 0; k < Hdim; k++) {
      float hv = (float)hbuf[0][tid * STR + k] + (float)hbuf[0][(tid + 8) * STR + k];
      s += hv * W_mlp[k];
    }
    out[b0 + tid] = sigm(s + b_mlp[0]);
  }
}

extern "C" void kernel_launch(void* const* d_in, const int* in_sizes, int n_in,
                              void* d_out, int out_size, void* d_ws, size_t ws_size,
                              hipStream_t stream) {
  const float* x     = (const float*)d_in[0];
  const float* hx0   = (const float*)d_in[1];
  const float* cx0   = (const float*)d_in[2];
  const float* W_ih  = (const float*)d_in[3];
  const float* W_hh  = (const float*)d_in[4];
  const float* b_ih  = (const float*)d_in[5];
  const float* b_hh  = (const float*)d_in[6];
  const float* W_mlp = (const float*)d_in[7];
  const float* b_mlp = (const float*)d_in[8];
  float* out = (float*)d_out;

  const int B = in_sizes[1] / Hdim;   // hx0 is [B, H]
  dim3 grid(B / BT), block(512);
  lstm_disc_kernel<<<grid, block, 0, stream>>>(x, hx0, cx0, W_ih, W_hh, b_ih,
                                               b_hh, W_mlp, b_mlp, out);
}

// Round 3
// 465.591 us; speedup vs baseline: 2.5144x; 1.2129x over previous
//
#include <hip/hip_runtime.h>

#define Hdim 128
#define Tlen 512
#define BT 8      // batch rows per block
#define STR 136   // padded LDS row stride in fp16 elems (272B = 17x16B)

typedef __attribute__((ext_vector_type(8))) _Float16 f16x8;
typedef __attribute__((ext_vector_type(2))) _Float16 f16x2;
typedef __attribute__((ext_vector_type(4))) float f32x4;

__device__ __forceinline__ f32x4 mfma_f16(f16x8 a, f16x8 b, f32x4 c) {
  return __builtin_amdgcn_mfma_f32_16x16x32_f16(a, b, c, 0, 0, 0);
}
__device__ __forceinline__ float sigm(float x) {
  return __builtin_amdgcn_rcpf(1.0f + __builtin_amdgcn_exp2f(x * -1.44269504f));
}
__device__ __forceinline__ float tanhx(float x) {
  float e = __builtin_amdgcn_exp2f(x * 2.88539008f);
  return 1.0f - 2.0f * __builtin_amdgcn_rcpf(e + 1.0f);
}
// lane i <- lane (i+8) mod 16 within each 16-lane DPP row == lane^8 swap.
// VALU-pipe cross-lane: replaces ds_bpermute shuffles (round-2's DS hog).
__device__ __forceinline__ float dpp_xor8(float v) {
  int r = __builtin_amdgcn_update_dpp(0, __builtin_bit_cast(int, v),
                                      0x128 /*row_ror:8*/, 0xF, 0xF, true);
  return __builtin_bit_cast(float, r);
}

// 256 blocks x 512 threads (8 waves, 2/SIMD). Block owns 8 batch rows, all T.
// MFMA 16x16x32 f16, gates-major: M=512 gate rows (32 tiles), N=16 (cols 0-7 =
// h fp16-hi per batch row, cols 8-15 = fp16 residual), K=128 + extra K-tile
// carrying [x,1]x[W_ih,bias]. Wave w owns tiles {w+8s} = gate types i,f,g,o of
// units 16w..16w+15 -> pointwise update fully in registers (c fp32-resident).
// Gate = hi-col + lo-col via DPP row_ror:8 (VALU), not shfl (DS pipe).
// x comes from global, prefetched 2 steps ahead (vmem pipe, L1-resident).
__global__ __launch_bounds__(512, 2)
void lstm_disc_kernel(const float* __restrict__ x, const float* __restrict__ hx0,
                      const float* __restrict__ cx0, const float* __restrict__ W_ih,
                      const float* __restrict__ W_hh, const float* __restrict__ b_ih,
                      const float* __restrict__ b_hh, const float* __restrict__ W_mlp,
                      const float* __restrict__ b_mlp, float* __restrict__ out) {
  __shared__ _Float16 hbuf0[16 * STR];
  __shared__ _Float16 hbuf1[16 * STR];

  const int tid  = threadIdx.x;
  const int w    = tid >> 6;          // wave 0..7
  const int lane = tid & 63;
  const int l16  = lane & 15;         // B col n / A row m
  const int quad = lane >> 4;         // 0..3
  const int b0   = blockIdx.x * BT;
  const int bb   = l16 & 7;           // batch row within block
  const bool hi_col = (l16 < 8);
  const int rbase = hi_col ? 0 : 2;   // C-rows this lane owns for the update
  const bool useb = (quad == 0) && hi_col;

  // ---- A fragments: W_hh (fp16) + extra tile [W_ih | bias | 0...] ----
  f16x8 wh[4][4], wx[4];
#pragma unroll
  for (int s = 0; s < 4; s++) {
    const int j = 16 * w + 128 * s + l16;       // gate row, type s
#pragma unroll
    for (int q = 0; q < 4; q++) {
      const float* p = W_hh + j * Hdim + q * 32 + quad * 8;
      f16x8 f;
#pragma unroll
      for (int e = 0; e < 8; e++) f[e] = (_Float16)p[e];
      wh[s][q] = f;
    }
    f16x8 g = 0;
    if (quad == 0) {
      g[0] = (_Float16)W_ih[j];
      g[1] = (_Float16)(b_ih[j] + b_hh[j]);
    }
    wx[s] = g;
  }
  // constant part of the x-column B fragment: [., 1, 0...] on active lanes
  f16x8 bxc = 0;
  if (useb) bxc[1] = (_Float16)1.0f;

  // ---- h0 -> LDS: rows 0-7 fp16 hi, rows 8-15 fp16 residual ----
  for (int i = tid; i < BT * Hdim; i += 512) {
    const int b = i >> 7, k = i & 127;
    float v = hx0[(b0 + b) * Hdim + k];
    _Float16 h = (_Float16)v;
    hbuf0[b * STR + k]       = h;
    hbuf0[(b + 8) * STR + k] = (_Float16)(v - (float)h);
  }

  // ---- c0 -> registers: lane owns units kb,kb+1 of batch bb ----
  const int kb = 16 * w + 4 * quad + rbase;     // even
  float c[2] = {cx0[(b0 + bb) * Hdim + kb], cx0[(b0 + bb) * Hdim + kb + 1]};

  const float* xp = x + (b0 + bb) * Tlen;
  float xv0 = xp[0];
  float xv1 = xp[1];

  __syncthreads();

  auto step = [&](const _Float16* __restrict__ src, _Float16* __restrict__ dst,
                  float xv) {
    // B frags: B[k=quad*8+e][n=l16]
    f16x8 bfrag[4];
#pragma unroll
    for (int q = 0; q < 4; q++)
      bfrag[q] = *(const f16x8*)&src[l16 * STR + q * 32 + quad * 8];

    f16x8 bx = bxc;
    if (useb) bx[0] = (_Float16)xv;

    f32x4 acc[4];
#pragma unroll
    for (int s = 0; s < 4; s++) {
      f32x4 a = {0.0f, 0.0f, 0.0f, 0.0f};
      a = mfma_f16(wx[s], bx, a);
#pragma unroll
      for (int q = 0; q < 4; q++) a = mfma_f16(wh[s][q], bfrag[q], a);
      acc[s] = a;
    }

    // hi/lo column cross-add via DPP (VALU pipe, no DS)
    float G[4][2];
#pragma unroll
    for (int s = 0; s < 4; s++) {
#pragma unroll
      for (int r2 = 0; r2 < 2; r2++) {
        float mine = acc[s][rbase + r2];
        float send = acc[s][(rbase ^ 2) + r2];
        G[s][r2] = mine + dpp_xor8(send);
      }
    }

    // LSTM pointwise (registers); write new h (hi + residual) to LDS
    f16x2 hhp, hlp;
#pragma unroll
    for (int r2 = 0; r2 < 2; r2++) {
      float iv = sigm(G[0][r2]);
      float fv = sigm(G[1][r2]);
      float gv = tanhx(G[2][r2]);
      float ov = sigm(G[3][r2]);
      float cn = fv * c[r2] + iv * gv;
      c[r2] = cn;
      float hv = ov * tanhx(cn);
      _Float16 hh = (_Float16)hv;
      hhp[r2] = hh;
      hlp[r2] = (_Float16)(hv - (float)hh);
    }
    *(f16x2*)&dst[bb * STR + kb]       = hhp;
    *(f16x2*)&dst[(bb + 8) * STR + kb] = hlp;

    __syncthreads();
  };

  for (int t = 0; t < Tlen; t += 2) {
    const int ta = (t + 2 < Tlen) ? t + 2 : Tlen - 1;
    const int tb = (t + 3 < Tlen) ? t + 3 : Tlen - 1;
    float xa = xp[ta];
    float xb = xp[tb];
    step(hbuf0, hbuf1, xv0);
    step(hbuf1, hbuf0, xv1);
    xv0 = xa;
    xv1 = xb;
  }

  // ---- epilogue: out[b] = sigmoid(h . W_mlp + b_mlp); final h in hbuf0 ----
  if (tid < BT) {
    float s = 0.0f;
#pragma unroll 8
    for (int k = 0; k < Hdim; k++) {
      float hv = (float)hbuf0[tid * STR + k] + (float)hbuf0[(tid + 8) * STR + k];
      s += hv * W_mlp[k];
    }
    out[b0 + tid] = sigm(s + b_mlp[0]);
  }
}

extern "C" void kernel_launch(void* const* d_in, const int* in_sizes, int n_in,
                              void* d_out, int out_size, void* d_ws, size_t ws_size,
                              hipStream_t stream) {
  const float* x     = (const float*)d_in[0];
  const float* hx0   = (const float*)d_in[1];
  const float* cx0   = (const float*)d_in[2];
  const float* W_ih  = (const float*)d_in[3];
  const float* W_hh  = (const float*)d_in[4];
  const float* b_ih  = (const float*)d_in[5];
  const float* b_hh  = (const float*)d_in[6];
  const float* W_mlp = (const float*)d_in[7];
  const float* b_mlp = (const float*)d_in[8];
  float* out = (float*)d_out;

  const int B = in_sizes[1] / Hdim;   // hx0 is [B, H]
  dim3 grid(B / BT), block(512);
  lstm_disc_kernel<<<grid, block, 0, stream>>>(x, hx0, cx0, W_ih, W_hh, b_ih,
                                               b_hh, W_mlp, b_mlp, out);
}

// Round 5
// 445.432 us; speedup vs baseline: 2.6282x; 1.0453x over previous
//
#include <hip/hip_runtime.h>

#define Hdim 128
#define Tlen 512
#define BT 8      // batch rows per block
#define STR 136   // padded LDS row stride in fp16 elems (272B = 17x16B)

typedef __attribute__((ext_vector_type(8))) _Float16 f16x8;
typedef __attribute__((ext_vector_type(2))) _Float16 f16x2;
typedef __attribute__((ext_vector_type(4))) float f32x4;

__device__ __forceinline__ f32x4 mfma_f16(f16x8 a, f16x8 b, f32x4 c) {
  return __builtin_amdgcn_mfma_f32_16x16x32_f16(a, b, c, 0, 0, 0);
}
// lane i <- lane (i+8) mod 16 within each 16-lane DPP row == lane^8 swap.
__device__ __forceinline__ float dpp_xor8(float v) {
  int r = __builtin_amdgcn_update_dpp(0, __builtin_bit_cast(int, v),
                                      0x128 /*row_ror:8*/, 0xF, 0xF, true);
  return __builtin_bit_cast(float, r);
}
// v_cvt_pkrtz_f16_f32: pack two f32 into two f16 (round toward zero)
__device__ __forceinline__ f16x2 pk16(float a, float b) {
  return __builtin_bit_cast(f16x2, __builtin_amdgcn_cvt_pkrtz(a, b));
}

// 256 blocks x 512 threads (8 waves, 2/SIMD). Block owns 8 batch rows, all T.
// MFMA 16x16x32 f16, gates-major: M=512 gate rows (32 tiles), N=16 (cols 0-7 =
// h fp16-hi per batch row, cols 8-15 = fp16 residual), K=128 + extra K-tile
// carrying x*W_ih. Wave w owns tiles {w+8s} = gate types i,f,g,o of units
// 16w..16w+15 -> pointwise fully in registers (c fp32-resident, 2 cells/lane).
// R4 VALU cuts: (1) bias rides the MFMA C-operand (no acc zero-init movs);
// (2) W rows pre-scaled by -log2e (i,f,o) / +2log2e (g) so sigma/tanh are
// rcp(1+exp2(G)) with no per-call mul; (3) v_cvt_pkrtz packs h hi/lo;
// (4) unroll 4. Gate = hi-col + lo-col via DPP row_ror:8 (VALU pipe).
__global__ __launch_bounds__(512, 2)
void lstm_disc_kernel(const float* __restrict__ x, const float* __restrict__ hx0,
                      const float* __restrict__ cx0, const float* __restrict__ W_ih,
                      const float* __restrict__ W_hh, const float* __restrict__ b_ih,
                      const float* __restrict__ b_hh, const float* __restrict__ W_mlp,
                      const float* __restrict__ b_mlp, float* __restrict__ out) {
  __shared__ _Float16 hbuf0[16 * STR];
  __shared__ _Float16 hbuf1[16 * STR];

  const int tid  = threadIdx.x;
  const int w    = tid >> 6;          // wave 0..7
  const int lane = tid & 63;
  const int l16  = lane & 15;         // B col n / A row m
  const int quad = lane >> 4;         // 0..3
  const int b0   = blockIdx.x * BT;
  const int bb   = l16 & 7;           // batch row within block
  const bool hi_col = (l16 < 8);
  const int rbase = hi_col ? 0 : 2;   // C-rows this lane owns for the update
  const bool useb = (quad == 0) && hi_col;

  // ---- A fragments: W_hh pre-scaled; wx = [W_ih | 0...]; bias_c in C-layout ----
  f16x8 wh[4][4], wx[4];
  f32x4 bias_c[4];
#pragma unroll
  for (int s = 0; s < 4; s++) {
    const float sc = (s == 2) ? 2.88539008f : -1.44269504f;  // g : i,f,o
    const int j = 16 * w + 128 * s + l16;       // gate row, type s
#pragma unroll
    for (int q = 0; q < 4; q++) {
      const float* p = W_hh + j * Hdim + q * 32 + quad * 8;
      f16x8 f;
#pragma unroll
      for (int e = 0; e < 8; e++) f[e] = (_Float16)(p[e] * sc);
      wh[s][q] = f;
    }
    f16x8 g = 0;
    if (quad == 0) g[0] = (_Float16)(W_ih[j] * sc);
    wx[s] = g;
    // bias in C/D layout (row m = quad*4+r, col l16); hi cols only so the
    // hi+lo cross-add counts it exactly once
    f32x4 bc;
#pragma unroll
    for (int r = 0; r < 4; r++) {
      const int j2 = 16 * w + 128 * s + quad * 4 + r;
      bc[r] = hi_col ? (b_ih[j2] + b_hh[j2]) * sc : 0.0f;
    }
    bias_c[s] = bc;
  }

  // ---- h0 -> LDS: rows 0-7 fp16 hi, rows 8-15 fp16 residual ----
  for (int i = tid; i < BT * Hdim; i += 512) {
    const int b = i >> 7, k = i & 127;
    float v = hx0[(b0 + b) * Hdim + k];
    _Float16 h = (_Float16)v;
    hbuf0[b * STR + k]       = h;
    hbuf0[(b + 8) * STR + k] = (_Float16)(v - (float)h);
  }

  // ---- c0 -> registers: lane owns units kb,kb+1 of batch bb ----
  const int kb = 16 * w + 4 * quad + rbase;     // even
  float c[2] = {cx0[(b0 + bb) * Hdim + kb], cx0[(b0 + bb) * Hdim + kb + 1]};

  const float* xp = x + (b0 + bb) * Tlen;
  float xv0 = xp[0], xv1 = xp[1], xv2 = xp[2], xv3 = xp[3];

  __syncthreads();

  auto step = [&](const _Float16* __restrict__ src, _Float16* __restrict__ dst,
                  float xv) {
    // B frags: B[k=quad*8+e][n=l16]
    f16x8 bfrag[4];
#pragma unroll
    for (int q = 0; q < 4; q++)
      bfrag[q] = *(const f16x8*)&src[l16 * STR + q * 32 + quad * 8];

    f16x8 bx = 0;
    if (useb) bx[0] = (_Float16)xv;

    f32x4 acc[4];
#pragma unroll
    for (int s = 0; s < 4; s++) {
      f32x4 a = mfma_f16(wx[s], bx, bias_c[s]);  // x*W_ih + bias, C-op init
#pragma unroll
      for (int q = 0; q < 4; q++) a = mfma_f16(wh[s][q], bfrag[q], a);
      acc[s] = a;
    }

    // hi/lo column cross-add via DPP (VALU pipe, no DS)
    float G[4][2];
#pragma unroll
    for (int s = 0; s < 4; s++) {
#pragma unroll
      for (int r2 = 0; r2 < 2; r2++) {
        float mine = acc[s][rbase + r2];
        float send = acc[s][(rbase ^ 2) + r2];
        G[s][r2] = mine + dpp_xor8(send);
      }
    }

    // LSTM pointwise; gates pre-scaled so no mul before exp2
    float hv[2];
#pragma unroll
    for (int r2 = 0; r2 < 2; r2++) {
      float iv = __builtin_amdgcn_rcpf(1.0f + __builtin_amdgcn_exp2f(G[0][r2]));
      float fv = __builtin_amdgcn_rcpf(1.0f + __builtin_amdgcn_exp2f(G[1][r2]));
      float gv = 1.0f - 2.0f * __builtin_amdgcn_rcpf(
                              __builtin_amdgcn_exp2f(G[2][r2]) + 1.0f);
      float ov = __builtin_amdgcn_rcpf(1.0f + __builtin_amdgcn_exp2f(G[3][r2]));
      float cn = fv * c[r2] + iv * gv;
      c[r2] = cn;
      float tc = 1.0f - 2.0f * __builtin_amdgcn_rcpf(
                              __builtin_amdgcn_exp2f(cn * 2.88539008f) + 1.0f);
      hv[r2] = ov * tc;
    }
    f16x2 hhp = pk16(hv[0], hv[1]);
    f16x2 hlp = pk16(hv[0] - (float)hhp[0], hv[1] - (float)hhp[1]);
    *(f16x2*)&dst[bb * STR + kb]       = hhp;
    *(f16x2*)&dst[(bb + 8) * STR + kb] = hlp;

    __syncthreads();
  };

  for (int t = 0; t < Tlen; t += 4) {
    const int tn = t + 4;
    const float xa = xp[(tn     < Tlen) ? tn     : Tlen - 1];
    const float xb = xp[(tn + 1 < Tlen) ? tn + 1 : Tlen - 1];
    const float xc = xp[(tn + 2 < Tlen) ? tn + 2 : Tlen - 1];
    const float xd = xp[(tn + 3 < Tlen) ? tn + 3 : Tlen - 1];
    step(hbuf0, hbuf1, xv0);
    step(hbuf1, hbuf0, xv1);
    step(hbuf0, hbuf1, xv2);
    step(hbuf1, hbuf0, xv3);
    xv0 = xa; xv1 = xb; xv2 = xc; xv3 = xd;
  }

  // ---- epilogue: out[b] = sigmoid(h . W_mlp + b_mlp); final h in hbuf0 ----
  if (tid < BT) {
    float s = 0.0f;
#pragma unroll 8
    for (int k = 0; k < Hdim; k++) {
      float hvv = (float)hbuf0[tid * STR + k] + (float)hbuf0[(tid + 8) * STR + k];
      s += hvv * W_mlp[k];
    }
    out[b0 + tid] = __builtin_amdgcn_rcpf(
        1.0f + __builtin_amdgcn_exp2f((s + b_mlp[0]) * -1.44269504f));
  }
}

extern "C" void kernel_launch(void* const* d_in, const int* in_sizes, int n_in,
                              void* d_out, int out_size, void* d_ws, size_t ws_size,
                              hipStream_t stream) {
  const float* x     = (const float*)d_in[0];
  const float* hx0   = (const float*)d_in[1];
  const float* cx0   = (const float*)d_in[2];
  const float* W_ih  = (const float*)d_in[3];
  const float* W_hh  = (const float*)d_in[4];
  const float* b_ih  = (const float*)d_in[5];
  const float* b_hh  = (const float*)d_in[6];
  const float* W_mlp = (const float*)d_in[7];
  const float* b_mlp = (const float*)d_in[8];
  float* out = (float*)d_out;

  const int B = in_sizes[1] / Hdim;   // hx0 is [B, H]
  dim3 grid(B / BT), block(512);
  lstm_disc_kernel<<<grid, block, 0, stream>>>(x, hx0, cx0, W_ih, W_hh, b_ih,
                                               b_hh, W_mlp, b_mlp, out);
}